// Round 3
// baseline (463.944 us; speedup 1.0000x reference)
//
#include <hip/hip_runtime.h>
#include <cstdint>

// Problem constants
#define TOKENS 16384      // BATCH(8) * SEQ(2048)
#define DMODEL 1024
#define NHEADS 16
#define HDIM   64

typedef __bf16  bf16x8 __attribute__((ext_vector_type(8)));
typedef ushort  u16x8  __attribute__((ext_vector_type(8)));
typedef ushort  u16x4  __attribute__((ext_vector_type(4)));
typedef float   f32x4  __attribute__((ext_vector_type(4)));

// fp32 -> bf16 (round-half-up; inputs are well-scaled normals, no overflow risk)
__device__ __forceinline__ ushort f2bf(float f) {
    union { float f; unsigned int i; } v; v.f = f;
    return (ushort)((v.i + 0x8000u) >> 16);
}
__device__ __forceinline__ f32x4 mfma16(bf16x8 a, bf16x8 b, f32x4 c) {
    return __builtin_amdgcn_mfma_f32_16x16x32_bf16(a, b, c, 0, 0, 0);
}
// async global->LDS direct copy, 16B per lane. LDS dest must be linear in lane.
__device__ __forceinline__ void gload_lds16(const void* g, void* l) {
    __builtin_amdgcn_global_load_lds(
        (const __attribute__((address_space(1))) unsigned int*)(uintptr_t)g,
        (__attribute__((address_space(3))) unsigned int*)(uintptr_t)l,
        16, 0, 0);
}
union BU { u16x8 u; bf16x8 b; };

// ---------------------------------------------------------------------------
// Elementwise fp32 -> bf16 convert, up to 4 tensors via blockIdx.y.
// ---------------------------------------------------------------------------
struct CvtArgs {
    const float* src[4];
    ushort*      dst[4];
};

__global__ __launch_bounds__(256) void cvt_f32_bf16(CvtArgs a)
{
    const float* __restrict__ s = a.src[blockIdx.y];
    ushort*      __restrict__ d = a.dst[blockIdx.y];
    const long i = ((long)blockIdx.x * 256 + threadIdx.x) * 8;
    const f32x4 v0 = *(const f32x4*)(s + i);
    const f32x4 v1 = *(const f32x4*)(s + i + 4);
    u16x8 p;
    #pragma unroll
    for (int j = 0; j < 4; j++) {
        p[j]     = f2bf(v0[j]);
        p[4 + j] = f2bf(v1[j]);
    }
    *(u16x8*)(d + i) = p;
}

// ---------------------------------------------------------------------------
// NT GEMM:  C[m,n] = sum_k A[m,k] * W[n,k] + bias[n]
// bf16 inputs; bf16 or fp32 output (template). MFMA fp32 accumulation.
// 128x128 tile, BK=32, 256 threads = 4 waves (2x2), global_load_lds width=16.
// 2-phase double-buffer, one barrier per K-step. XCD-chunked swizzle (T1).
// T2 LDS swizzle (rule #21: gload_lds writes linearly, so the permutation is
// applied to the GLOBAL SOURCE k-slice at staging and to the READ address):
//   LDS granule (row r, slot s) holds k-slice  s ^ ((r>>1)&3).
// Per-16-lane read group this spreads the 16B granules over all 8 bank-slots
// (2 lanes each = free) instead of 2 slots (8-way, the 1.26e7 conflicts).
// ---------------------------------------------------------------------------
#define BM 128
#define BN 128
#define BK 32

struct GemmArgs {
    const ushort* A[3];
    const ushort* W[3];
    const float*  Bi[3];
    void*         C[3];
};

template<int BF16OUT>
__global__ __launch_bounds__(256) void gemm_bt_bias(GemmArgs args, int N, int K)
{
    __shared__ __align__(16) ushort As[2][BM * BK];   // 2 x 8 KB
    __shared__ __align__(16) ushort Bs[2][BN * BK];   // 2 x 8 KB

    // XCD-chunked swizzle (bijective: total % 8 == 0 since gridDim.x == 8)
    const int gx = gridDim.x, gy = gridDim.y;
    const int lin   = (blockIdx.z * gy + blockIdx.y) * gx + blockIdx.x;
    const int total = gx * gy * gridDim.z;
    const int cpx   = total >> 3;
    const int swz   = (lin & 7) * cpx + (lin >> 3);
    const int bz    = swz / (gx * gy);
    const int rem   = swz - bz * gx * gy;
    const int by    = rem / gx;
    const int bx    = rem - by * gx;

    const ushort* __restrict__ A  = args.A[bz];
    const ushort* __restrict__ W  = args.W[bz];
    const float*  __restrict__ Bi = args.Bi[bz];

    const int tid  = threadIdx.x;
    const int wave = tid >> 6;
    const int lane = tid & 63;
    const int wm = wave >> 1;          // 0..1 row-wave
    const int wn = wave & 1;           // 0..1 col-wave
    const long rowBase = (long)by * BM;
    const long colBase = (long)bx * BN;

    // staging: chunk c (0..511) -> LDS granule c (linear, HW requirement).
    // Global source: row c>>2, k-slice  (c&3) ^ ((c>>3)&3)  (T2 inverse swz).
    const int c0  = tid;
    const int c1  = tid + 256;
    const int r0s = c0 >> 2, k0s = (((c0 & 3) ^ ((c0 >> 3) & 3)) * 8);
    const int r1s = c1 >> 2, k1s = (((c1 & 3) ^ ((c1 >> 3) & 3)) * 8);

    // fragment addressing: row-part fr, swizzled k-slot fks (same for all
    // sub-tiles since row = base16*i + fr and (row>>1)&3 == (fr>>1)&3)
    const int fr  = lane & 15;                              // m (A) / n (B)
    const int fks = (((lane >> 4) ^ ((fr >> 1) & 3)) * 8);  // swizzled k slot

    f32x4 acc[4][4];
    #pragma unroll
    for (int i = 0; i < 4; i++)
        #pragma unroll
        for (int j = 0; j < 4; j++)
            acc[i][j] = (f32x4){0.f, 0.f, 0.f, 0.f};

    auto STAGE = [&](int b, int kt) {
        gload_lds16(A + (rowBase + r0s) * (long)K + kt + k0s, &As[b][c0 * 8]);
        gload_lds16(A + (rowBase + r1s) * (long)K + kt + k1s, &As[b][c1 * 8]);
        gload_lds16(W + (colBase + r0s) * (long)K + kt + k0s, &Bs[b][c0 * 8]);
        gload_lds16(W + (colBase + r1s) * (long)K + kt + k1s, &Bs[b][c1 * 8]);
    };

    const int nt = K / BK;
    int cur = 0;
    STAGE(0, 0);
    __syncthreads();   // compiler drains vmcnt(0) before barrier: tile 0 ready

    for (int t = 0; t < nt; ++t) {
        if (t + 1 < nt) STAGE(cur ^ 1, (t + 1) * BK);   // prefetch next tile

        bf16x8 af[4], bfv[4];
        #pragma unroll
        for (int i = 0; i < 4; i++)
            af[i] = *(const bf16x8*)&As[cur][(wm * 64 + i * 16 + fr) * BK + fks];
        #pragma unroll
        for (int j = 0; j < 4; j++)
            bfv[j] = *(const bf16x8*)&Bs[cur][(wn * 64 + j * 16 + fr) * BK + fks];

        #pragma unroll
        for (int i = 0; i < 4; i++)
            #pragma unroll
            for (int j = 0; j < 4; j++)
                acc[i][j] = mfma16(af[i], bfv[j], acc[i][j]);

        __syncthreads();   // drains lgkm (our reads) + vmcnt (next tile) once
        cur ^= 1;
    }

    // epilogue: C layout col=lane&15, row=(lane>>4)*4+reg
    const int qd = lane >> 4;
    #pragma unroll
    for (int j = 0; j < 4; j++) {
        const long col = colBase + wn * 64 + j * 16 + fr;
        const float bv = Bi[col];
        #pragma unroll
        for (int i = 0; i < 4; i++) {
            const long r0 = rowBase + wm * 64 + i * 16 + qd * 4;
            #pragma unroll
            for (int r = 0; r < 4; r++) {
                const float val = acc[i][j][r] + bv;
                if (BF16OUT)
                    ((ushort*)args.C[bz])[(r0 + r) * (long)N + col] = f2bf(val);
                else
                    ((float*)args.C[bz])[(r0 + r) * (long)N + col] = val;
            }
        }
    }
}

// ---------------------------------------------------------------------------
// Fused per-token attention (16x16 head-gram) + LayerNorm — MFMA version.
// One wave per token; 4 tokens per 256-thread block. bf16 in, bf16 out.
// Pm rows padded to 40 elems (80B): pa-read granule = 5*fr+hi covers all 8
// bank-slots per 16-lane group (was 64B rows -> 8-way conflict).
// ---------------------------------------------------------------------------
#define PMS 40    // Pm row stride in elements

__global__ __launch_bounds__(256) void attn_ln_mfma(
    const ushort* __restrict__ Qp, const ushort* __restrict__ Kp,
    const ushort* __restrict__ Vp,
    const float* __restrict__ lng, const float* __restrict__ lnb,
    ushort* __restrict__ O)
{
    __shared__ __align__(16) ushort Vs[4][16 * 64];    // per-wave V rows [g][d]
    __shared__ __align__(16) ushort Pm[4][16 * PMS];   // per-wave P [h][k], k<16 live

    const int tid  = threadIdx.x;
    const int w    = tid >> 6;
    const int lane = tid & 63;
    const long tok  = (long)blockIdx.x * 4 + w;
    const long base = tok * DMODEL;

    // stage V (row-major [g][d]) via direct global->LDS, linear in lane
    gload_lds16(Vp + base +       lane * 8, &Vs[w][      lane * 8]);
    gload_lds16(Vp + base + 512 + lane * 8, &Vs[w][512 + lane * 8]);

    // zero the k=16..31 half of Pm: lane covers row lane&15, cols 16+(l>>4)*4..+3
    *(u16x4*)&Pm[w][(lane & 15) * PMS + 16 + (lane >> 4) * 4] = (u16x4){0, 0, 0, 0};

    const int fr = lane & 15;          // g (QK cols) / h (P rows on read)
    const int fs = (lane >> 4) * 8;    // k-slice

    // QK^T fragments directly from global (token row is 2KB, L2/LLC-resident)
    const bf16x8 aq0 = *(const bf16x8*)(Qp + base + fr * 64 + fs);
    const bf16x8 aq1 = *(const bf16x8*)(Qp + base + fr * 64 + fs + 32);
    const bf16x8 bk0 = *(const bf16x8*)(Kp + base + fr * 64 + fs);
    const bf16x8 bk1 = *(const bf16x8*)(Kp + base + fr * 64 + fs + 32);

    f32x4 e = (f32x4){0.f, 0.f, 0.f, 0.f};
    e = mfma16(aq0, bk0, e);
    e = mfma16(aq1, bk1, e);
    // lane holds E[h=(lane>>4)*4+r][g=fr]

    // softmax over g = across the 16 lanes of this quad-group; store P^T to LDS
    #pragma unroll
    for (int r = 0; r < 4; ++r) {
        const float x = e[r] * 0.03125f;              // 1/sqrt(1024)
        float mx = x;
        #pragma unroll
        for (int m = 1; m < 16; m <<= 1) mx = fmaxf(mx, __shfl_xor(mx, m, 64));
        const float ex = __expf(x - mx);
        float sm = ex;
        #pragma unroll
        for (int m = 1; m < 16; m <<= 1) sm += __shfl_xor(sm, m, 64);
        Pm[w][((lane >> 4) * 4 + r) * PMS + fr] = f2bf(ex / sm);
    }

    __syncthreads();   // drains vmcnt (V staging) + lgkm (P writes)

    // PV: A-frag = P[h=fr][k=fs..fs+7] (zero for k>=16); one MFMA per d-block
    const bf16x8 pa = *(const bf16x8*)&Pm[w][fr * PMS + fs];

    f32x4 o[4];
    #pragma unroll
    for (int dblk = 0; dblk < 4; ++dblk) {
        BU bu; bu.u = (u16x8){0, 0, 0, 0, 0, 0, 0, 0};
        if (lane < 32) {   // k = fs+j < 16: real V rows; else stay zero (P=0 too)
            #pragma unroll
            for (int j = 0; j < 8; ++j)
                bu.u[j] = Vs[w][(fs + j) * 64 + dblk * 16 + fr];
        }
        o[dblk] = mfma16(pa, bu.b, (f32x4){0.f, 0.f, 0.f, 0.f});
    }
    // lane holds out[h=(lane>>4)*4+r][d=dblk*16+fr]

    // LayerNorm over 1024: 16 regs/lane x 64 lanes cover it exactly once
    float s1 = 0.f, s2 = 0.f;
    #pragma unroll
    for (int dblk = 0; dblk < 4; ++dblk)
        #pragma unroll
        for (int r = 0; r < 4; ++r) { const float v = o[dblk][r]; s1 += v; s2 += v * v; }
    #pragma unroll
    for (int m = 1; m < 64; m <<= 1) {
        s1 += __shfl_xor(s1, m, 64);
        s2 += __shfl_xor(s2, m, 64);
    }
    const float mu   = s1 * (1.f / DMODEL);
    const float var  = s2 * (1.f / DMODEL) - mu * mu;
    const float rstd = rsqrtf(var + 1e-5f);

    #pragma unroll
    for (int dblk = 0; dblk < 4; ++dblk) {
        #pragma unroll
        for (int r = 0; r < 4; ++r) {
            const int h = (lane >> 4) * 4 + r;
            const int i = h * HDIM + dblk * 16 + fr;
            O[base + i] = f2bf((o[dblk][r] - mu) * rstd * lng[i] + lnb[i]);
        }
    }
}

// ---------------------------------------------------------------------------
// launch — ws-size-adaptive chunked pipeline.
// ws layout: [4x bf16 weights | per-chunk: qb,kb,vb,qp,vp (all bf16)]
// kp (bf16 K-proj) borrows the d_out chunk (dead before final GEMM overwrite);
// attention writes bf16 output over qb (dead after GEMM1).
// ---------------------------------------------------------------------------
extern "C" void kernel_launch(void* const* d_in, const int* in_sizes, int n_in,
                              void* d_out, int out_size, void* d_ws, size_t ws_size,
                              hipStream_t stream)
{
    const float* query = (const float*)d_in[0];
    const float* key   = (const float*)d_in[1];
    const float* value = (const float*)d_in[2];
    const float* Wq = (const float*)d_in[3];
    const float* bq = (const float*)d_in[4];
    const float* Wk = (const float*)d_in[5];
    const float* bk = (const float*)d_in[6];
    const float* Wv = (const float*)d_in[7];
    const float* bv = (const float*)d_in[8];
    const float* lng = (const float*)d_in[9];
    const float* lnb = (const float*)d_in[10];
    const float* Wo = (const float*)d_in[11];
    const float* bo = (const float*)d_in[12];
    float* out = (float*)d_out;

    const long WELEMS = (long)DMODEL * DMODEL;       // 1Mi elems per weight

    ushort* wq_b = (ushort*)d_ws;
    ushort* wk_b = wq_b + WELEMS;
    ushort* wv_b = wk_b + WELEMS;
    ushort* wo_b = wv_b + WELEMS;
    ushort* cbuf = wo_b + WELEMS;                    // per-chunk region

    // bytes needed: 8MB weights + CM*1024*(5 bf16 bufs * 2B) = 8MB + CM*10240
    int NC = 1;
    while (NC < 128 &&
           (size_t)(8 * WELEMS) + (size_t)(TOKENS / NC) * DMODEL * 10 > ws_size)
        NC <<= 1;
    const int CM = TOKENS / NC;                 // tokens per chunk (mult of 128)
    const size_t CE = (size_t)CM * DMODEL;      // elems per chunk buffer

    ushort* qb = cbuf;            // query bf16; later reused for attn bf16 out
    ushort* kb = qb + CE;
    ushort* vb = kb + CE;
    ushort* qp = vb + CE;         // bf16 Q-projection (attn input)
    ushort* vp = qp + CE;         // bf16 V-projection (attn input)

    // 0) convert weights fp32 -> bf16 (once)
    {
        CvtArgs cw;
        cw.src[0] = Wq; cw.src[1] = Wk; cw.src[2] = Wv; cw.src[3] = Wo;
        cw.dst[0] = wq_b; cw.dst[1] = wk_b; cw.dst[2] = wv_b; cw.dst[3] = wo_b;
        cvt_f32_bf16<<<dim3((unsigned)(WELEMS / 2048), 4), 256, 0, stream>>>(cw);
    }

    for (int c = 0; c < NC; ++c) {
        const size_t off = (size_t)c * CE;
        ushort* kp = (ushort*)(out + off);      // bf16 scratch in d_out chunk

        // 1) convert this chunk's query/key/value fp32 -> bf16
        {
            CvtArgs ci;
            ci.src[0] = query + off; ci.src[1] = key + off; ci.src[2] = value + off;
            ci.src[3] = query;  // unused (z<3)
            ci.dst[0] = qb; ci.dst[1] = kb; ci.dst[2] = vb; ci.dst[3] = qb;
            cvt_f32_bf16<<<dim3((unsigned)(CE / 2048), 3), 256, 0, stream>>>(ci);
        }

        // 2) fused QKV projections, bf16 outputs (z picks q/k/v)
        GemmArgs g1;
        g1.A[0] = qb;    g1.A[1] = kb;   g1.A[2] = vb;
        g1.W[0] = wq_b;  g1.W[1] = wk_b; g1.W[2] = wv_b;
        g1.Bi[0] = bq;   g1.Bi[1] = bk;  g1.Bi[2] = bv;
        g1.C[0] = qp;    g1.C[1] = kp;   g1.C[2] = vp;
        gemm_bt_bias<1><<<dim3(DMODEL / BN, CM / BM, 3), 256, 0, stream>>>(
            g1, DMODEL, DMODEL);

        // 3) per-token attention + LayerNorm -> bf16 into qb (dead after GEMM1)
        attn_ln_mfma<<<CM / 4, 256, 0, stream>>>(qp, kp, vp, lng, lnb, qb);

        // 4) output projection -> d_out chunk fp32 (overwrites kp scratch)
        GemmArgs g2;
        g2.A[0] = g2.A[1] = g2.A[2] = qb;
        g2.W[0] = g2.W[1] = g2.W[2] = wo_b;
        g2.Bi[0] = g2.Bi[1] = g2.Bi[2] = bo;
        g2.C[0] = g2.C[1] = g2.C[2] = out + off;
        gemm_bt_bias<0><<<dim3(DMODEL / BN, CM / BM, 1), 256, 0, stream>>>(
            g2, DMODEL, DMODEL);
    }
}

// Round 4
// 432.004 us; speedup vs baseline: 1.0739x; 1.0739x over previous
//
#include <hip/hip_runtime.h>
#include <cstdint>

// Problem constants
#define TOKENS 16384      // BATCH(8) * SEQ(2048)
#define DMODEL 1024
#define NHEADS 16
#define HDIM   64

typedef __bf16  bf16x8 __attribute__((ext_vector_type(8)));
typedef ushort  u16x8  __attribute__((ext_vector_type(8)));
typedef ushort  u16x4  __attribute__((ext_vector_type(4)));
typedef float   f32x4  __attribute__((ext_vector_type(4)));

// fp32 -> bf16 (round-half-up; inputs are well-scaled normals, no overflow risk)
__device__ __forceinline__ ushort f2bf(float f) {
    union { float f; unsigned int i; } v; v.f = f;
    return (ushort)((v.i + 0x8000u) >> 16);
}
__device__ __forceinline__ f32x4 mfma16(bf16x8 a, bf16x8 b, f32x4 c) {
    return __builtin_amdgcn_mfma_f32_16x16x32_bf16(a, b, c, 0, 0, 0);
}
// async global->LDS direct copy, 16B per lane. LDS dest must be linear in lane.
__device__ __forceinline__ void gload_lds16(const void* g, void* l) {
    __builtin_amdgcn_global_load_lds(
        (const __attribute__((address_space(1))) unsigned int*)(uintptr_t)g,
        (__attribute__((address_space(3))) unsigned int*)(uintptr_t)l,
        16, 0, 0);
}
union BU { u16x8 u; bf16x8 b; };

// ---------------------------------------------------------------------------
// Elementwise fp32 -> bf16 convert, up to 4 tensors via blockIdx.y.
// ---------------------------------------------------------------------------
struct CvtArgs {
    const float* src[4];
    ushort*      dst[4];
};

__global__ __launch_bounds__(256) void cvt_f32_bf16(CvtArgs a)
{
    const float* __restrict__ s = a.src[blockIdx.y];
    ushort*      __restrict__ d = a.dst[blockIdx.y];
    const long i = ((long)blockIdx.x * 256 + threadIdx.x) * 8;
    const f32x4 v0 = *(const f32x4*)(s + i);
    const f32x4 v1 = *(const f32x4*)(s + i + 4);
    u16x8 p;
    #pragma unroll
    for (int j = 0; j < 4; j++) {
        p[j]     = f2bf(v0[j]);
        p[4 + j] = f2bf(v1[j]);
    }
    *(u16x8*)(d + i) = p;
}

// ---------------------------------------------------------------------------
// NT GEMM, 8-phase-style deep pipeline (T1+T2+T3+T4+T5):
//   C[m,n] = sum_k A[m,k] * W[n,k] + bias[n]
// 256x256 tile, BK=32, 512 threads = 8 waves (2M x 4N), per-wave 128x64.
// LDS: 4-slot ring (4 x (16KB A + 16KB B) = 128 KiB), staged 3 K-tiles ahead.
// Per K-tile: 2 phases {ds_read || 2x global_load_lds -> setprio(1) 16 MFMA
// setprio(0) -> raw s_barrier}; ONE counted s_waitcnt vmcnt(8) per K-tile
// (never 0 in the main loop).
//
// vmcnt arithmetic (2 loads/phase, strict FIFO: ..A(t),B(t),A(t+1),B(t+1)..):
//   end of K-tile X: outstanding = A,B(X+2), A,B(X+3) = 8 -> vmcnt(8) retires
//   K-tile X+1 (read next iteration). Prologue: 12 issued, vmcnt(8) retires
//   K-tile 0. Tail (no more stages): vmcnt(4) then vmcnt(0).
// Slot safety: slot (X+3)&3 = (X-1)&3 was last ds_read in K-tile X-1, whose
// reads are lgkm-retired before X-1's end barrier; stage issues after it.
// T2 swizzle (verified R3: conflicts -> 0): LDS granule (row r, slot s)
// holds k-slice s ^ ((r>>1)&3); inverse applied to global source address.
// ---------------------------------------------------------------------------
#define BM2 256
#define BN2 256
#define BK2 32

struct GemmArgs {
    const ushort* A[3];
    const ushort* W[3];
    const float*  Bi[3];
    void*         C[3];
};

#define G256_READ_B(slot)                                                     \
    { _Pragma("unroll")                                                       \
      for (int n = 0; n < 4; ++n)                                             \
          bf[n] = *(const bf16x8*)&Bs[slot][(wn * 64 + n * 16 + fr) * BK2 + fks]; }

#define G256_READ_A(slot, mh)                                                 \
    { _Pragma("unroll")                                                       \
      for (int m = 0; m < 4; ++m)                                             \
          af[m] = *(const bf16x8*)&As[slot][(wm * 128 + (mh) * 64 + m * 16 + fr) * BK2 + fks]; }

#define G256_MFMA(mh)                                                         \
    { __builtin_amdgcn_s_setprio(1);                                          \
      _Pragma("unroll")                                                       \
      for (int m = 0; m < 4; ++m)                                             \
          _Pragma("unroll")                                                   \
          for (int n = 0; n < 4; ++n)                                         \
              acc[(mh) * 4 + m][n] = mfma16(af[m], bf[n], acc[(mh) * 4 + m][n]); \
      __builtin_amdgcn_s_setprio(0); }

template<int BF16OUT>
__global__ __launch_bounds__(512) void gemm256(GemmArgs args, int N, int K)
{
    __shared__ __align__(16) ushort As[4][BM2 * BK2];   // 4 x 16 KB
    __shared__ __align__(16) ushort Bs[4][BN2 * BK2];   // 4 x 16 KB

    // bijective XCD-chunked swizzle (m204 variant, any nwg)
    const int gx = gridDim.x, gy = gridDim.y;
    const int lin = (blockIdx.z * gy + blockIdx.y) * gx + blockIdx.x;
    const int nwg = gx * gy * gridDim.z;
    const int q = nwg >> 3, r = nwg & 7;
    const int xcd = lin & 7, loc = lin >> 3;
    const int swz = (xcd < r ? xcd * (q + 1) : r * (q + 1) + (xcd - r) * q) + loc;
    const int bz  = swz / (gx * gy);
    const int rem = swz - bz * gx * gy;
    const int by  = rem / gx;
    const int bx  = rem - by * gx;

    const ushort* __restrict__ A  = args.A[bz];
    const ushort* __restrict__ W  = args.W[bz];
    const float*  __restrict__ Bi = args.Bi[bz];

    const int tid  = threadIdx.x;
    const int wave = tid >> 6;
    const int lane = tid & 63;
    const int wm = wave >> 2;          // 0..1 row-wave
    const int wn = wave & 3;           // 0..3 col-wave
    const long rowBase = (long)by * BM2;
    const long colBase = (long)bx * BN2;

    // staging granules: g = tid and tid+512 cover the 1024 16B-granules of one
    // 256x32 tile; LDS dest g*16 is linear in lane per wave (HW requirement).
    // Global source for granule g: row g>>2, k-slice (g&3)^((g>>3)&3) (T2 inv).
    const int gA0 = tid, gA1 = tid + 512;
    const long aOff0 = (long)(gA0 >> 2) * K + (((gA0 & 3) ^ ((gA0 >> 3) & 3)) * 8);
    const long aOff1 = (long)(gA1 >> 2) * K + (((gA1 & 3) ^ ((gA1 >> 3) & 3)) * 8);
    const ushort* Abase = A + rowBase * K;
    const ushort* Wbase = W + colBase * K;

    // fragment addressing: swizzled k-slot, same for all 16-row sub-tiles
    const int fr  = lane & 15;
    const int fks = (((lane >> 4) ^ ((fr >> 1) & 3)) * 8);

    f32x4 acc[8][4];
    #pragma unroll
    for (int m = 0; m < 8; ++m)
        #pragma unroll
        for (int n = 0; n < 4; ++n)
            acc[m][n] = (f32x4){0.f, 0.f, 0.f, 0.f};

    auto stageA = [&](int slot, int kt) {
        gload_lds16(Abase + aOff0 + (long)kt * BK2, &As[slot][gA0 * 8]);
        gload_lds16(Abase + aOff1 + (long)kt * BK2, &As[slot][gA1 * 8]);
    };
    auto stageB = [&](int slot, int kt) {
        gload_lds16(Wbase + aOff0 + (long)kt * BK2, &Bs[slot][gA0 * 8]);
        gload_lds16(Wbase + aOff1 + (long)kt * BK2, &Bs[slot][gA1 * 8]);
    };

    const int nt = K / BK2;            // 32 for K=1024 (requires nt >= 4)

    // prologue: stage K-tiles 0,1,2 (12 loads); retire K-tile 0 (vmcnt(8))
    stageA(0, 0); stageB(0, 0);
    stageA(1, 1); stageB(1, 1);
    stageA(2, 2); stageB(2, 2);
    asm volatile("s_waitcnt vmcnt(8)" ::: "memory");
    __builtin_amdgcn_s_barrier();

    bf16x8 af[4], bf[4];

    for (int X = 0; X < nt - 3; ++X) {
        const int slot = X & 3, st = (X + 3) & 3;
        // phase even: m-half 0  (B-frags read once per K-tile, reused in odd)
        G256_READ_B(slot);
        G256_READ_A(slot, 0);
        stageA(st, X + 3);
        G256_MFMA(0);
        __builtin_amdgcn_s_barrier();
        // phase odd: m-half 1
        G256_READ_A(slot, 1);
        stageB(st, X + 3);
        G256_MFMA(1);
        asm volatile("s_waitcnt vmcnt(8)" ::: "memory");   // K-tile X+1 landed
        __builtin_amdgcn_s_barrier();
    }
    { // X = nt-3: no staging left; outstanding A,B(nt-2),A,B(nt-1)
        const int slot = (nt - 3) & 3;
        G256_READ_B(slot);
        G256_READ_A(slot, 0);
        G256_MFMA(0);
        __builtin_amdgcn_s_barrier();
        G256_READ_A(slot, 1);
        G256_MFMA(1);
        asm volatile("s_waitcnt vmcnt(4)" ::: "memory");   // K-tile nt-2 landed
        __builtin_amdgcn_s_barrier();
    }
    { // X = nt-2
        const int slot = (nt - 2) & 3;
        G256_READ_B(slot);
        G256_READ_A(slot, 0);
        G256_MFMA(0);
        __builtin_amdgcn_s_barrier();
        G256_READ_A(slot, 1);
        G256_MFMA(1);
        asm volatile("s_waitcnt vmcnt(0)" ::: "memory");   // K-tile nt-1 landed
        __builtin_amdgcn_s_barrier();
    }
    { // X = nt-1
        const int slot = (nt - 1) & 3;
        G256_READ_B(slot);
        G256_READ_A(slot, 0);
        G256_MFMA(0);
        __builtin_amdgcn_s_barrier();
        G256_READ_A(slot, 1);
        G256_MFMA(1);
    }

    // epilogue: C layout col=lane&15, row=(lane>>4)*4+reg
    const int qd = lane >> 4;
    #pragma unroll
    for (int n = 0; n < 4; ++n) {
        const long col = colBase + wn * 64 + n * 16 + fr;
        const float bv = Bi[col];
        #pragma unroll
        for (int m = 0; m < 8; ++m) {
            const long r0 = rowBase + wm * 128 + m * 16 + qd * 4;
            #pragma unroll
            for (int r2 = 0; r2 < 4; ++r2) {
                const float val = acc[m][n][r2] + bv;
                if (BF16OUT)
                    ((ushort*)args.C[bz])[(r0 + r2) * (long)N + col] = f2bf(val);
                else
                    ((float*)args.C[bz])[(r0 + r2) * (long)N + col] = val;
            }
        }
    }
}

// ---------------------------------------------------------------------------
// Fused per-token attention (16x16 head-gram) + LayerNorm — MFMA version.
// One wave per token; 4 tokens per 256-thread block. bf16 in, bf16 out.
// Pm rows padded to 40 elems (80B): pa-read granule = 5*fr+hi covers all 8
// bank-slots per 16-lane group.
// ---------------------------------------------------------------------------
#define PMS 40    // Pm row stride in elements

__global__ __launch_bounds__(256) void attn_ln_mfma(
    const ushort* __restrict__ Qp, const ushort* __restrict__ Kp,
    const ushort* __restrict__ Vp,
    const float* __restrict__ lng, const float* __restrict__ lnb,
    ushort* __restrict__ O)
{
    __shared__ __align__(16) ushort Vs[4][16 * 64];    // per-wave V rows [g][d]
    __shared__ __align__(16) ushort Pm[4][16 * PMS];   // per-wave P [h][k], k<16 live

    const int tid  = threadIdx.x;
    const int w    = tid >> 6;
    const int lane = tid & 63;
    const long tok  = (long)blockIdx.x * 4 + w;
    const long base = tok * DMODEL;

    // stage V (row-major [g][d]) via direct global->LDS, linear in lane
    gload_lds16(Vp + base +       lane * 8, &Vs[w][      lane * 8]);
    gload_lds16(Vp + base + 512 + lane * 8, &Vs[w][512 + lane * 8]);

    // zero the k=16..31 half of Pm: lane covers row lane&15, cols 16+(l>>4)*4..+3
    *(u16x4*)&Pm[w][(lane & 15) * PMS + 16 + (lane >> 4) * 4] = (u16x4){0, 0, 0, 0};

    const int fr = lane & 15;          // g (QK cols) / h (P rows on read)
    const int fs = (lane >> 4) * 8;    // k-slice

    // QK^T fragments directly from global (token row is 2KB, L2/LLC-resident)
    const bf16x8 aq0 = *(const bf16x8*)(Qp + base + fr * 64 + fs);
    const bf16x8 aq1 = *(const bf16x8*)(Qp + base + fr * 64 + fs + 32);
    const bf16x8 bk0 = *(const bf16x8*)(Kp + base + fr * 64 + fs);
    const bf16x8 bk1 = *(const bf16x8*)(Kp + base + fr * 64 + fs + 32);

    f32x4 e = (f32x4){0.f, 0.f, 0.f, 0.f};
    e = mfma16(aq0, bk0, e);
    e = mfma16(aq1, bk1, e);
    // lane holds E[h=(lane>>4)*4+r][g=fr]

    // softmax over g = across the 16 lanes of this quad-group; store P^T to LDS
    #pragma unroll
    for (int r = 0; r < 4; ++r) {
        const float x = e[r] * 0.03125f;              // 1/sqrt(1024)
        float mx = x;
        #pragma unroll
        for (int m = 1; m < 16; m <<= 1) mx = fmaxf(mx, __shfl_xor(mx, m, 64));
        const float ex = __expf(x - mx);
        float sm = ex;
        #pragma unroll
        for (int m = 1; m < 16; m <<= 1) sm += __shfl_xor(sm, m, 64);
        Pm[w][((lane >> 4) * 4 + r) * PMS + fr] = f2bf(ex / sm);
    }

    __syncthreads();   // drains vmcnt (V staging) + lgkm (P writes)

    // PV: A-frag = P[h=fr][k=fs..fs+7] (zero for k>=16); one MFMA per d-block
    const bf16x8 pa = *(const bf16x8*)&Pm[w][fr * PMS + fs];

    f32x4 o[4];
    #pragma unroll
    for (int dblk = 0; dblk < 4; ++dblk) {
        BU bu; bu.u = (u16x8){0, 0, 0, 0, 0, 0, 0, 0};
        if (lane < 32) {   // k = fs+j < 16: real V rows; else stay zero (P=0 too)
            #pragma unroll
            for (int j = 0; j < 8; ++j)
                bu.u[j] = Vs[w][(fs + j) * 64 + dblk * 16 + fr];
        }
        o[dblk] = mfma16(pa, bu.b, (f32x4){0.f, 0.f, 0.f, 0.f});
    }
    // lane holds out[h=(lane>>4)*4+r][d=dblk*16+fr]

    // LayerNorm over 1024: 16 regs/lane x 64 lanes cover it exactly once
    float s1 = 0.f, s2 = 0.f;
    #pragma unroll
    for (int dblk = 0; dblk < 4; ++dblk)
        #pragma unroll
        for (int r = 0; r < 4; ++r) { const float v = o[dblk][r]; s1 += v; s2 += v * v; }
    #pragma unroll
    for (int m = 1; m < 64; m <<= 1) {
        s1 += __shfl_xor(s1, m, 64);
        s2 += __shfl_xor(s2, m, 64);
    }
    const float mu   = s1 * (1.f / DMODEL);
    const float var  = s2 * (1.f / DMODEL) - mu * mu;
    const float rstd = rsqrtf(var + 1e-5f);

    #pragma unroll
    for (int dblk = 0; dblk < 4; ++dblk) {
        #pragma unroll
        for (int r = 0; r < 4; ++r) {
            const int h = (lane >> 4) * 4 + r;
            const int i = h * HDIM + dblk * 16 + fr;
            O[base + i] = f2bf((o[dblk][r] - mu) * rstd * lng[i] + lnb[i]);
        }
    }
}

// ---------------------------------------------------------------------------
// launch — ws-size-adaptive chunked pipeline.
// ws layout: [4x bf16 weights | per-chunk: qb,kb,vb,qp,vp (all bf16)]
// kp (bf16 K-proj) borrows the d_out chunk (dead before final GEMM overwrite);
// attention writes bf16 output over qb (dead after GEMM1).
// ---------------------------------------------------------------------------
extern "C" void kernel_launch(void* const* d_in, const int* in_sizes, int n_in,
                              void* d_out, int out_size, void* d_ws, size_t ws_size,
                              hipStream_t stream)
{
    const float* query = (const float*)d_in[0];
    const float* key   = (const float*)d_in[1];
    const float* value = (const float*)d_in[2];
    const float* Wq = (const float*)d_in[3];
    const float* bq = (const float*)d_in[4];
    const float* Wk = (const float*)d_in[5];
    const float* bk = (const float*)d_in[6];
    const float* Wv = (const float*)d_in[7];
    const float* bv = (const float*)d_in[8];
    const float* lng = (const float*)d_in[9];
    const float* lnb = (const float*)d_in[10];
    const float* Wo = (const float*)d_in[11];
    const float* bo = (const float*)d_in[12];
    float* out = (float*)d_out;

    const long WELEMS = (long)DMODEL * DMODEL;       // 1Mi elems per weight

    ushort* wq_b = (ushort*)d_ws;
    ushort* wk_b = wq_b + WELEMS;
    ushort* wv_b = wk_b + WELEMS;
    ushort* wo_b = wv_b + WELEMS;
    ushort* cbuf = wo_b + WELEMS;                    // per-chunk region

    // bytes needed: 8MB weights + CM*1024*(5 bf16 bufs * 2B) = 8MB + CM*10240
    // NC capped at 64 so CM stays a multiple of 256 (BM2 tile).
    int NC = 1;
    while (NC < 64 &&
           (size_t)(8 * WELEMS) + (size_t)(TOKENS / NC) * DMODEL * 10 > ws_size)
        NC <<= 1;
    const int CM = TOKENS / NC;                 // tokens per chunk (mult of 256)
    const size_t CE = (size_t)CM * DMODEL;      // elems per chunk buffer

    ushort* qb = cbuf;            // query bf16; later reused for attn bf16 out
    ushort* kb = qb + CE;
    ushort* vb = kb + CE;
    ushort* qp = vb + CE;         // bf16 Q-projection (attn input)
    ushort* vp = qp + CE;         // bf16 V-projection (attn input)

    // 0) convert weights fp32 -> bf16 (once)
    {
        CvtArgs cw;
        cw.src[0] = Wq; cw.src[1] = Wk; cw.src[2] = Wv; cw.src[3] = Wo;
        cw.dst[0] = wq_b; cw.dst[1] = wk_b; cw.dst[2] = wv_b; cw.dst[3] = wo_b;
        cvt_f32_bf16<<<dim3((unsigned)(WELEMS / 2048), 4), 256, 0, stream>>>(cw);
    }

    for (int c = 0; c < NC; ++c) {
        const size_t off = (size_t)c * CE;
        ushort* kp = (ushort*)(out + off);      // bf16 scratch in d_out chunk

        // 1) convert this chunk's query/key/value fp32 -> bf16
        {
            CvtArgs ci;
            ci.src[0] = query + off; ci.src[1] = key + off; ci.src[2] = value + off;
            ci.src[3] = query;  // unused (z<3)
            ci.dst[0] = qb; ci.dst[1] = kb; ci.dst[2] = vb; ci.dst[3] = qb;
            cvt_f32_bf16<<<dim3((unsigned)(CE / 2048), 3), 256, 0, stream>>>(ci);
        }

        // 2) fused QKV projections, bf16 outputs (z picks q/k/v)
        GemmArgs g1;
        g1.A[0] = qb;    g1.A[1] = kb;   g1.A[2] = vb;
        g1.W[0] = wq_b;  g1.W[1] = wk_b; g1.W[2] = wv_b;
        g1.Bi[0] = bq;   g1.Bi[1] = bk;  g1.Bi[2] = bv;
        g1.C[0] = qp;    g1.C[1] = kp;   g1.C[2] = vp;
        gemm256<1><<<dim3(DMODEL / BN2, CM / BM2, 3), 512, 0, stream>>>(
            g1, DMODEL, DMODEL);

        // 3) per-token attention + LayerNorm -> bf16 into qb (dead after GEMM1)
        attn_ln_mfma<<<CM / 4, 256, 0, stream>>>(qp, kp, vp, lng, lnb, qb);

        // 4) output projection -> d_out chunk fp32 (overwrites kp scratch)
        GemmArgs g2;
        g2.A[0] = g2.A[1] = g2.A[2] = qb;
        g2.W[0] = g2.W[1] = g2.W[2] = wo_b;
        g2.Bi[0] = g2.Bi[1] = g2.Bi[2] = bo;
        g2.C[0] = g2.C[1] = g2.C[2] = out + off;
        gemm256<0><<<dim3(DMODEL / BN2, CM / BM2, 1), 512, 0, stream>>>(
            g2, DMODEL, DMODEL);
    }
}